// Round 15
// baseline (377.744 us; speedup 1.0000x reference)
//
#include <hip/hip_runtime.h>
#include <cmath>

#define B_ 128
#define L_ 128
#define N_ 16
#define E_ 128
#define D_ 128
#define H_ 100
#define G_ 300   // 3*H
#define C_ 104
#define T_ (B_*L_)
#define XST 600  // xW row stride (cols 0..299 fwd, 300..599 bwd)

typedef short bf16x8 __attribute__((ext_vector_type(8)));
typedef float f32x4 __attribute__((ext_vector_type(4)));

__device__ __forceinline__ short f2bf(float f) {
  unsigned u = __builtin_bit_cast(unsigned, f);
  u += 0x7fffu + ((u >> 16) & 1u);   // round-to-nearest-even
  return (short)(u >> 16);
}

// ---------------------------------------------------------------------------
// K1 (MFMA): fused embedding gather + W_c projection + tree agg + max/relu
// (unchanged)
// ---------------------------------------------------------------------------
__global__ __launch_bounds__(256, 2) void k_tree(
    const int* __restrict__ tokens, const int* __restrict__ parents,
    const float* __restrict__ emb, const float* __restrict__ Wc_w,
    const float* __restrict__ Wc_b, float* __restrict__ enc) {
  __shared__ float s_h[4][N_][132];
  __shared__ int s_par[4][N_];
  const int tid = threadIdx.x;
  const int wid = tid >> 6;
  const int l = tid & 63;
  const int lr = l & 15;
  const int lk = l >> 4;

  bf16x8 Bf[8][4];
#pragma unroll
  for (int nt = 0; nt < 8; ++nt)
#pragma unroll
    for (int ks = 0; ks < 4; ++ks) {
      const float* src = Wc_w + (size_t)(nt * 16 + lr) * E_ + ks * 32 + lk * 8;
      const float4 p0 = *reinterpret_cast<const float4*>(src);
      const float4 p1 = *reinterpret_cast<const float4*>(src + 4);
      bf16x8 v;
      v[0] = f2bf(p0.x); v[1] = f2bf(p0.y); v[2] = f2bf(p0.z); v[3] = f2bf(p0.w);
      v[4] = f2bf(p1.x); v[5] = f2bf(p1.y); v[6] = f2bf(p1.z); v[7] = f2bf(p1.w);
      Bf[nt][ks] = v;
    }
  float Wb[8];
#pragma unroll
  for (int nt = 0; nt < 8; ++nt) Wb[nt] = Wc_b[nt * 16 + lr];

  const int wave_gid = blockIdx.x * 4 + wid;
  const int wave_tot = gridDim.x * 4;

  for (int t = wave_gid; t < T_; t += wave_tot) {
    const int tok = tokens[t * N_ + lr];
    if (lk == 0) s_par[wid][lr] = parents[t * N_ + lr];

    const float* arow = emb + (size_t)tok * E_ + lk * 8;
    bf16x8 Af[4];
#pragma unroll
    for (int ks = 0; ks < 4; ++ks) {
      const float4 p0 = *reinterpret_cast<const float4*>(arow + ks * 32);
      const float4 p1 = *reinterpret_cast<const float4*>(arow + ks * 32 + 4);
      bf16x8 v;
      v[0] = f2bf(p0.x); v[1] = f2bf(p0.y); v[2] = f2bf(p0.z); v[3] = f2bf(p0.w);
      v[4] = f2bf(p1.x); v[5] = f2bf(p1.y); v[6] = f2bf(p1.z); v[7] = f2bf(p1.w);
      Af[ks] = v;
    }

    f32x4 acc[8];
#pragma unroll
    for (int nt = 0; nt < 8; ++nt) {
      f32x4 a = {0.f, 0.f, 0.f, 0.f};
#pragma unroll
      for (int ks = 0; ks < 4; ++ks)
        a = __builtin_amdgcn_mfma_f32_16x16x32_bf16(Af[ks], Bf[nt][ks], a, 0, 0, 0);
      acc[nt] = a;
    }

#pragma unroll
    for (int nt = 0; nt < 8; ++nt) {
      const float wb = Wb[nt];
#pragma unroll
      for (int r = 0; r < 4; ++r)
        s_h[wid][lk * 4 + r][nt * 16 + lr] = acc[nt][r] + wb;
    }

#pragma unroll
    for (int j = N_ - 1; j >= 1; --j) {
      const int p = s_par[wid][j];
      s_h[wid][p][l]      += s_h[wid][j][l];
      s_h[wid][p][l + 64] += s_h[wid][j][l + 64];
    }
    float m0 = s_h[wid][0][l], m1 = s_h[wid][0][l + 64];
#pragma unroll
    for (int j = 1; j < N_; ++j) {
      m0 = fmaxf(m0, s_h[wid][j][l]);
      m1 = fmaxf(m1, s_h[wid][j][l + 64]);
    }
    enc[(size_t)t * D_ + l]      = fmaxf(m0, 0.f);
    enc[(size_t)t * D_ + l + 64] = fmaxf(m1, 0.f);
  }
}

// ---------------------------------------------------------------------------
// K2 (MFMA): xW[m][n] = enc[m][:] . Wcat[n][:] + bihcat[n]  (unchanged)
// ---------------------------------------------------------------------------
__global__ __launch_bounds__(256, 2) void k_xw(
    const float* __restrict__ enc,
    const float* __restrict__ Wih_f, const float* __restrict__ bih_f,
    const float* __restrict__ Wih_b, const float* __restrict__ bih_b,
    float* __restrict__ xW) {
  const int tid = threadIdx.x;
  const int wid = tid >> 6, l = tid & 63;
  const int lr = l & 15, lk = l >> 4;
  const int wave_gid = blockIdx.x * 4 + wid;   // 0..1279
  const int ns = wave_gid / 128;               // n-slice 0..9 (4 n-tiles each)
  const int mg = wave_gid % 128;               // m-group

  bf16x8 Bf[4][4];
  float bi[4];
  bool valid[4];
#pragma unroll
  for (int i = 0; i < 4; ++i) {
    const int n = (ns * 4 + i) * 16 + lr;
    valid[i] = (n < XST);
    const int nc = valid[i] ? n : (XST - 1);   // clamp: no OOB reads
    const float* Wrow = (nc < G_) ? Wih_f + (size_t)nc * D_
                                  : Wih_b + (size_t)(nc - G_) * D_;
    bi[i] = (nc < G_) ? bih_f[nc] : bih_b[nc - G_];
#pragma unroll
    for (int ks = 0; ks < 4; ++ks) {
      const float* src = Wrow + ks * 32 + lk * 8;
      const float4 p0 = *reinterpret_cast<const float4*>(src);
      const float4 p1 = *reinterpret_cast<const float4*>(src + 4);
      bf16x8 v;
      v[0] = f2bf(p0.x); v[1] = f2bf(p0.y); v[2] = f2bf(p0.z); v[3] = f2bf(p0.w);
      v[4] = f2bf(p1.x); v[5] = f2bf(p1.y); v[6] = f2bf(p1.z); v[7] = f2bf(p1.w);
      Bf[i][ks] = v;
    }
  }

  for (int mt = mg; mt < T_ / 16; mt += 128) {
    const float* arow = enc + (size_t)(mt * 16 + lr) * D_ + lk * 8;
    bf16x8 Af[4];
#pragma unroll
    for (int ks = 0; ks < 4; ++ks) {
      const float4 p0 = *reinterpret_cast<const float4*>(arow + ks * 32);
      const float4 p1 = *reinterpret_cast<const float4*>(arow + ks * 32 + 4);
      bf16x8 v;
      v[0] = f2bf(p0.x); v[1] = f2bf(p0.y); v[2] = f2bf(p0.z); v[3] = f2bf(p0.w);
      v[4] = f2bf(p1.x); v[5] = f2bf(p1.y); v[6] = f2bf(p1.z); v[7] = f2bf(p1.w);
      Af[ks] = v;
    }

#pragma unroll
    for (int i = 0; i < 4; ++i) {
      f32x4 a = {0.f, 0.f, 0.f, 0.f};
#pragma unroll
      for (int ks = 0; ks < 4; ++ks)
        a = __builtin_amdgcn_mfma_f32_16x16x32_bf16(Af[ks], Bf[i][ks], a, 0, 0, 0);
      if (valid[i]) {
        const int n = (ns * 4 + i) * 16 + lr;
        float* dst = xW + (size_t)(mt * 16 + lk * 4) * XST + n;
#pragma unroll
        for (int r = 0; r < 4; ++r) dst[r * XST] = a[r] + bi[i];
      }
    }
  }
}

// ---------------------------------------------------------------------------
// K3 (v3): sequential GRU scan. One 320-thread block (5 waves) per (dir,b).
// Round-11 counters: v2 (640 thr, split rows) = 1530 cyc/step, latency-bound
// (VALUBusy 27%, VGPR 52, HBM 3%). v3 removes the s_part split round-trip
// (full 100-float row per worker, 25 float4 = ~105 VGPR, forced resident by
// __launch_bounds__(320,1) -- v1's plain (320) gave VGPR_Count=64 + L2
// re-stream, round-5 evidence) and halves barrier participation (10->5
// waves). Verify via counters: resident => VGPR ~130+, FETCH ~20MB;
// spilled => FETCH explosion (revert signal).
// ---------------------------------------------------------------------------
__global__ __launch_bounds__(320, 1) void k_gru(
    const float* __restrict__ xW,
    const float* __restrict__ Whh_f, const float* __restrict__ bhh_f,
    const float* __restrict__ Whh_b, const float* __restrict__ bhh_b,
    float* __restrict__ pooled) {
  const int tid = threadIdx.x;
  const int dir = blockIdx.x >> 7;
  const int b = blockIdx.x & 127;
  const float* Whh = dir ? Whh_b : Whh_f;
  const float* bhh = dir ? bhh_b : bhh_f;
  const float* xrow0 = xW + (size_t)b * L_ * XST + dir * G_;

  __shared__ __align__(16) float s_h[2][104];   // h double-buffer (100 used)
  __shared__ float s_hW[G_];

  const bool worker = tid < G_;
  // Whh[g][0:100] -> 25 float4 VGPRs (rows are 400B = 16B-aligned)
  float4 wv[25];
  float bias = 0.f;
  if (worker) {
    const float4* wr = reinterpret_cast<const float4*>(Whh + (size_t)tid * H_);
#pragma unroll
    for (int i = 0; i < 25; ++i) wv[i] = wr[i];
    bias = bhh[tid];
  }

  // activation-thread state (tid < 100): x biases already folded into xW
  float xr = 0.f, xz = 0.f, xn = 0.f;
  if (tid < H_) {
    const int t0 = dir ? (L_ - 1) : 0;
    const float* xp = xrow0 + (size_t)t0 * XST;
    xr = xp[tid]; xz = xp[tid + H_]; xn = xp[tid + 2 * H_];
  }
  if (tid < 104) { s_h[0][tid] = 0.f; s_h[1][tid] = 0.f; }
  float hmax = -1e30f;
  __syncthreads();

  for (int t = 0; t < L_; ++t) {
    const int cur = t & 1, nxt = cur ^ 1;

    // prefetch next step's x (hidden under worker phase + barrier)
    float xr_n = 0.f, xz_n = 0.f, xn_n = 0.f;
    if (tid < H_ && t + 1 < L_) {
      const int tt = dir ? (L_ - 2 - t) : (t + 1);
      const float* xp = xrow0 + (size_t)tt * XST;
      xr_n = xp[tid]; xz_n = xp[tid + H_]; xn_n = xp[tid + 2 * H_];
    }

    if (worker) {  // full-row dot: 25 broadcast float4 LDS reads, 4 accums
      const float4* hv = reinterpret_cast<const float4*>(&s_h[cur][0]);
      float a0 = 0.f, a1 = 0.f, a2 = 0.f, a3 = 0.f;
#pragma unroll
      for (int i = 0; i < 25; ++i) {
        const float4 h4 = hv[i];
        a0 += h4.x * wv[i].x; a1 += h4.y * wv[i].y;
        a2 += h4.z * wv[i].z; a3 += h4.w * wv[i].w;
      }
      s_hW[tid] = bias + (a0 + a1) + (a2 + a3);
    }
    __syncthreads();

    if (tid < H_) {
      const float hr = s_hW[tid], hz = s_hW[tid + H_], hn = s_hW[tid + 2 * H_];
      const float r = 1.f / (1.f + __expf(-(xr + hr)));
      const float z = 1.f / (1.f + __expf(-(xz + hz)));
      const float e2 = __expf(2.f * (xn + r * hn));
      const float n = 1.f - 2.f / (e2 + 1.f);      // tanh, overflow-safe
      const float hp = s_h[cur][tid];
      const float hnew = (1.f - z) * n + z * hp;
      hmax = fmaxf(hmax, hnew);
      s_h[nxt][tid] = hnew;
      xr = xr_n; xz = xz_n; xn = xn_n;
    }
    __syncthreads();
  }
  if (tid < H_) pooled[((size_t)dir * B_ + b) * H_ + tid] = hmax;
}

// ---------------------------------------------------------------------------
// K4: classifier (unchanged)
// ---------------------------------------------------------------------------
__global__ __launch_bounds__(128) void k_cls(
    const float* __restrict__ pooled, const float* __restrict__ lbl_w,
    const float* __restrict__ lbl_b, float* __restrict__ out) {
  const int b = blockIdx.x;
  const int tid = threadIdx.x;
  __shared__ float s_p[2 * H_];
  if (tid < H_) {
    s_p[tid] = pooled[(size_t)b * H_ + tid];
    s_p[tid + H_] = pooled[((size_t)B_ + b) * H_ + tid];
  }
  __syncthreads();
  if (tid < C_) {
    float acc = lbl_b[tid];
    const float* wr = lbl_w + (size_t)tid * 2 * H_;
#pragma unroll
    for (int k = 0; k < 2 * H_; ++k) acc += s_p[k] * wr[k];
    out[(size_t)b * C_ + tid] = acc;
  }
}

extern "C" void kernel_launch(void* const* d_in, const int* in_sizes, int n_in,
                              void* d_out, int out_size, void* d_ws,
                              size_t ws_size, hipStream_t stream) {
  const int* tokens = (const int*)d_in[0];
  const int* parents = (const int*)d_in[1];
  const float* emb = (const float*)d_in[2];
  const float* Wc_w = (const float*)d_in[3];
  const float* Wc_b = (const float*)d_in[4];
  const float* Wih_f = (const float*)d_in[5];
  const float* Whh_f = (const float*)d_in[6];
  const float* bih_f = (const float*)d_in[7];
  const float* bhh_f = (const float*)d_in[8];
  const float* Wih_b = (const float*)d_in[9];
  const float* Whh_b = (const float*)d_in[10];
  const float* bih_b = (const float*)d_in[11];
  const float* bhh_b = (const float*)d_in[12];
  const float* lbl_w = (const float*)d_in[13];
  const float* lbl_b = (const float*)d_in[14];
  float* out = (float*)d_out;

  float* enc = (float*)d_ws;                  // T*D         =  8.0 MB
  float* xW = enc + (size_t)T_ * D_;          // T*600       = 37.5 MB
  float* pooled = xW + (size_t)T_ * XST;      // 2*B*H       =  0.1 MB

  k_tree<<<512, 256, 0, stream>>>(tokens, parents, emb, Wc_w, Wc_b, enc);
  k_xw<<<320, 256, 0, stream>>>(enc, Wih_f, bih_f, Wih_b, bih_b, xW);
  k_gru<<<256, 320, 0, stream>>>(xW, Whh_f, bhh_f, Whh_b, bhh_b, pooled);
  k_cls<<<B_, 128, 0, stream>>>(pooled, lbl_w, lbl_b, out);
}